// Round 12
// baseline (2314.230 us; speedup 1.0000x reference)
//
#include <hip/hip_runtime.h>
#include <math.h>

#define HH 512
#define VV 32000
#define BB 64
#define SS 64
#define TT 64
#define H3 1536

// ---- workspace layout (float offsets); wbf (8,192,000 f) aliases [0,8192000)
// which is all dead after the recurrence. ----
#define WS_GIEMBBF 0LL          // 4096*1536 ushort
#define WS_UKBF    3145728LL    // 4096*512 ushort
#define WS_ENCBF   4194304LL    // 4096*512 ushort
#define WS_EMBBF   5242880LL    // 4096*512 ushort
#define WS_WCATBF  6291456LL    // 2048*512 ushort (rows 0..511 = Wa bf16)
#define WS_WIHC3   6815744LL    // 1536*512 ushort (rows j*3+g, ctx half of W_ih)
#define WS_WIHE    7208960LL    // 1536*512 ushort (emb half of W_ih)
#define WS_UABF    7602176LL    // 512*512 ushort
#define WS_WHH3    7733248LL    // 1536*512 ushort (rows j*3+g of W_hh)
#define WS_BCAT    8126464LL    // 2048 f
#define WS_QBUF    8128512LL    // 64*512 f   (q for t=0, no bias)
#define WS_QPART   8161280LL    // 16*64*512 f (q partials)
#define WS_CTXBF   8685568LL    // 64*512 ushort
#define WS_H32     8701952LL    // 2 x 64*512 f
#define WS_HBF     8767488LL    // 2 x 64*512 ushort
#define WS_HSALL   8800256LL    // 4096*512 ushort (rows b*T+t) -- LIVE after recurrence
#define WS_FLAGS   9848832LL    // 64 ints
// end ~9,848,896 f = 39.4 MB

// output layout (floats)
#define OUT_HT  ((long long)BB*TT*VV)
#define OUT_ATT (OUT_HT + (long long)BB*HH)

typedef __attribute__((ext_vector_type(8))) short bf16x8;
typedef __attribute__((ext_vector_type(4))) float f32x4;

__device__ inline unsigned short f2b(float x) {
  unsigned u = __builtin_bit_cast(unsigned, x);
  unsigned r = (u + 0x7FFF + ((u >> 16) & 1)) >> 16;
  return (unsigned short)r;
}
__device__ inline float bc(unsigned u) { return __builtin_bit_cast(float, u); }
__device__ inline float b2f(unsigned short h) { return bc(((unsigned)h) << 16); }
__device__ inline float frcp(float x) { return __builtin_amdgcn_rcpf(x); }
__device__ inline float tanh_fast(float x) { return 1.f - 2.f * frcp(__expf(2.f * x) + 1.f); }
__device__ inline float sigm(float x) { return frcp(1.f + __expf(-x)); }

#define GLDS(gp, lp) __builtin_amdgcn_global_load_lds( \
    (const __attribute__((address_space(1))) void*)(gp), \
    (__attribute__((address_space(3))) void*)(lp), 16, 0, 0)

// ---------------------------------------------------------------------------
// prep kernels
// ---------------------------------------------------------------------------
__global__ __launch_bounds__(256) void build_wcat_kernel(const float* __restrict__ Wa,
    const float* __restrict__ Whh, const float* __restrict__ ba,
    const float* __restrict__ bhh, unsigned short* __restrict__ wcatbf,
    float* __restrict__ bcat)
{
  long long i = (long long)blockIdx.x * 256 + threadIdx.x;   // 2048*512
  int j = (int)(i >> 9), k = (int)(i & 511);
  float v = (j < HH) ? Wa[(long long)j*HH + k] : Whh[(long long)(j - HH)*HH + k];
  wcatbf[i] = f2b(v);
  if (i < 2048) bcat[i] = (i < HH) ? ba[i] : bhh[i - HH];
}

// o[(j*3+g)][k] = Wsrc[g*512+j][ofs+k]; Wsrc row stride = ld
__global__ __launch_bounds__(256) void build_g3_kernel(const float* __restrict__ Wsrc,
    unsigned short* __restrict__ o, int ld, int ofs)
{
  long long i = (long long)blockIdx.x * 256 + threadIdx.x;   // 1536*512
  int rp = (int)(i >> 9), k = (int)(i & 511);
  int j = rp / 3, g = rp - j * 3;
  o[i] = f2b(Wsrc[((long long)(g*512 + j))*ld + ofs + k]);
}

// wihebf[j][k] = W_ih[j][k]  (emb half)
__global__ __launch_bounds__(256) void build_wihe_kernel(const float* __restrict__ W_ih,
    unsigned short* __restrict__ o)
{
  long long i = (long long)blockIdx.x * 256 + threadIdx.x;   // 1536*512
  o[i] = f2b(W_ih[(long long)(i >> 9)*1024 + (i & 511)]);
}

__global__ __launch_bounds__(256) void cvt_f2b_kernel(const float* __restrict__ in,
    unsigned short* __restrict__ outp, long long n)
{
  long long i = ((long long)blockIdx.x * 256 + threadIdx.x) * 4;
  if (i >= n) return;
  float4 v = *(const float4*)(in + i);
  ushort4 r = { f2b(v.x), f2b(v.y), f2b(v.z), f2b(v.w) };
  *(ushort4*)(outp + i) = r;
}

// embbf row m = t*64+b  <-  emb[tok(b,t)]
__global__ __launch_bounds__(256) void build_embbf_kernel(const float* __restrict__ emb,
    const int* __restrict__ tgt, unsigned short* __restrict__ embbf)
{
  const int m = blockIdx.x, t = m >> 6, b = m & 63;
  const int tk = (t == 0) ? 0 : tgt[b*TT + t - 1];
  const float* src = emb + (long long)tk*HH;
  unsigned short* dst = embbf + (long long)m*HH;
  const int i = threadIdx.x;
  dst[i] = f2b(src[i]);
  dst[i + 256] = f2b(src[i + 256]);
}

__global__ __launch_bounds__(256) void hinit_kernel(const float* __restrict__ eh,
    unsigned short* __restrict__ hbf0, float* __restrict__ h320)
{
  int i = blockIdx.x * 256 + threadIdx.x;   // 32768
  float v = eh[i];
  hbf0[i] = f2b(v);
  h320[i] = v;
}

// ---------------------------------------------------------------------------
// Generic NT MFMA GEMM: C[m][n] = A[m,:512].B[n,:512] + bias[n]
// ---------------------------------------------------------------------------
template<int OUTBF>
__global__ __launch_bounds__(256) void mfma_nt(const unsigned short* __restrict__ A,
    const unsigned short* __restrict__ Bw, const float* __restrict__ bias,
    void* __restrict__ Cv, long long ldc)
{
  __shared__ unsigned short As[128*32];
  __shared__ unsigned short Bs[128*32];
  const int tid = threadIdx.x;
  const int w = tid >> 6, l = tid & 63;
  const int m0 = blockIdx.y * 128, n0 = blockIdx.x * 128;
  const int wr = w >> 1, wc = w & 1;

  f32x4 acc[4][4];
  #pragma unroll
  for (int i = 0; i < 4; i++)
    #pragma unroll
    for (int j = 0; j < 4; j++) acc[i][j] = (f32x4){0.f, 0.f, 0.f, 0.f};

  const int srow = l >> 2;
  const int scol = (l & 3) * 8;

  for (int k0 = 0; k0 < HH; k0 += 32) {
    __syncthreads();
    #pragma unroll
    for (int q = 0; q < 2; ++q) {
      int r = w*32 + q*16 + srow;
      GLDS(A  + (long long)(m0 + r)*HH + k0 + scol, As + r*32 + scol);
      GLDS(Bw + (long long)(n0 + r)*HH + k0 + scol, Bs + r*32 + scol);
    }
    __syncthreads();

    bf16x8 a[4], b[4];
    #pragma unroll
    for (int mi = 0; mi < 4; mi++)
      a[mi] = *(const bf16x8*)&As[(wr*64 + mi*16 + (l & 15))*32 + (l >> 4)*8];
    #pragma unroll
    for (int ni = 0; ni < 4; ni++)
      b[ni] = *(const bf16x8*)&Bs[(wc*64 + ni*16 + (l & 15))*32 + (l >> 4)*8];
    #pragma unroll
    for (int mi = 0; mi < 4; mi++)
      #pragma unroll
      for (int ni = 0; ni < 4; ni++)
        acc[mi][ni] = __builtin_amdgcn_mfma_f32_16x16x32_bf16(a[mi], b[ni], acc[mi][ni], 0, 0, 0);
  }

  #pragma unroll
  for (int mi = 0; mi < 4; mi++) {
    #pragma unroll
    for (int ni = 0; ni < 4; ni++) {
      int col = n0 + wc*64 + ni*16 + (l & 15);
      float bb = bias[col];
      #pragma unroll
      for (int r2 = 0; r2 < 4; r2++) {
        int row = m0 + wr*64 + mi*16 + (l >> 4)*4 + r2;
        float v = acc[mi][ni][r2] + bb;
        if (OUTBF) ((unsigned short*)Cv)[(long long)row*ldc + col] = f2b(v);
        else       ((float*)Cv)[(long long)row*ldc + col] = v;
      }
    }
  }
}

// ---------------------------------------------------------------------------
// qinit: qbuf[64][512] = h0 @ Wa^T (no bias). grid 4, 256 thr.
// ---------------------------------------------------------------------------
__global__ __launch_bounds__(256) void qinit_mfma(
    const unsigned short* __restrict__ hbf_r, const unsigned short* __restrict__ wabf,
    float* __restrict__ qbuf)
{
  __shared__ unsigned short As[64*32];
  __shared__ unsigned short Bs[128*32];
  const int tid = threadIdx.x;
  const int w = tid >> 6, l = tid & 63;
  const int n0 = blockIdx.x * 128;
  const int wr = w >> 1, wc = w & 1;

  f32x4 acc[2][4];
  #pragma unroll
  for (int i = 0; i < 2; i++)
    #pragma unroll
    for (int j = 0; j < 4; j++) acc[i][j] = (f32x4){0.f, 0.f, 0.f, 0.f};

  const int ar = tid >> 2;
  const int ac8 = (tid & 3) * 8;

  for (int k0 = 0; k0 < HH; k0 += 32) {
    __syncthreads();
    GLDS(hbf_r + (long long)ar*HH + k0 + ac8, As + ar*32 + ac8);
    #pragma unroll
    for (int q = 0; q < 2; ++q) {
      int r = q*64 + ar;
      GLDS(wabf + (long long)(n0 + r)*HH + k0 + ac8, Bs + r*32 + ac8);
    }
    __syncthreads();

    bf16x8 a[2], b[4];
    #pragma unroll
    for (int mi = 0; mi < 2; mi++)
      a[mi] = *(const bf16x8*)&As[(wr*32 + mi*16 + (l & 15))*32 + (l >> 4)*8];
    #pragma unroll
    for (int ni = 0; ni < 4; ni++)
      b[ni] = *(const bf16x8*)&Bs[(wc*64 + ni*16 + (l & 15))*32 + (l >> 4)*8];
    #pragma unroll
    for (int mi = 0; mi < 2; mi++)
      #pragma unroll
      for (int ni = 0; ni < 4; ni++)
        acc[mi][ni] = __builtin_amdgcn_mfma_f32_16x16x32_bf16(a[mi], b[ni], acc[mi][ni], 0, 0, 0);
  }

  #pragma unroll
  for (int mi = 0; mi < 2; mi++) {
    #pragma unroll
    for (int ni = 0; ni < 4; ni++) {
      int col = n0 + wc*64 + ni*16 + (l & 15);
      #pragma unroll
      for (int r2 = 0; r2 < 4; r2++) {
        int row = wr*32 + mi*16 + (l >> 4)*4 + r2;
        qbuf[(long long)row*512 + col] = acc[mi][ni][r2];
      }
    }
  }
}

// ---------------------------------------------------------------------------
// Fused step: grid 80 x 512.
//   blocks [0,64): attn for batch b  -> ctxbf, then release-add flags[t]
//   blocks [64,80): acquire-spin on flags[t]==64, then gh+gic+gates+qPart
// ---------------------------------------------------------------------------
__global__ __launch_bounds__(512) void step_fused(int t, int first, int last,
    const float* __restrict__ qbuf, float* __restrict__ qPart,
    const float* __restrict__ bcat, const unsigned short* __restrict__ ukbf,
    const unsigned short* __restrict__ encbf, const float* __restrict__ Va,
    const float* __restrict__ bvp, unsigned short* __restrict__ ctxbf,
    float* __restrict__ attn_out,
    const unsigned short* __restrict__ hbf_r,
    const unsigned short* __restrict__ wihc3bf, const unsigned short* __restrict__ whh3bf,
    const unsigned short* __restrict__ wabf, const unsigned short* __restrict__ giembbf,
    const float* __restrict__ h32_r, float* __restrict__ h32_w,
    unsigned short* __restrict__ hbf_w, unsigned short* __restrict__ hsall,
    float* __restrict__ out_ht, int* __restrict__ flags)
{
  const int bid = blockIdx.x, tid = threadIdx.x;
  const int w = tid >> 6, l = tid & 63;

  // gates-role LDS
  __shared__ unsigned short As[64*32];   // ctx tile
  __shared__ unsigned short Hs[64*32];   // h tile
  __shared__ unsigned short Bs[96*32];   // wihc3 rows
  __shared__ unsigned short Cs[96*32];   // whh3 rows
  __shared__ unsigned short Was[512*32]; // Wa k-slice
  __shared__ unsigned short hnewp[64*40];
  __shared__ float gl[64*100];
  __shared__ float hl[64*100];
  // attn-role LDS
  __shared__ float qs2[8][68];
  __shared__ float vsh[8][68];
  __shared__ float sc[SS], sw[SS];

  if (bid < 64) {
    // ================= attn role, b = bid =================
    const int b = bid;
    {
      const int c = tid;
      float q = bcat[c];
      if (first) {
        q += qbuf[(long long)b*512 + c];
      } else {
        #pragma unroll
        for (int i = 0; i < 16; ++i)
          q += qPart[(long long)i*32768 + b*512 + c];
      }
      qs2[c >> 6][c & 63] = q;
      vsh[c >> 6][c & 63] = Va[c];
    }
    __syncthreads();

    {
      const int s = tid >> 3, sub = tid & 7;
      const uint4* up = (const uint4*)(ukbf + ((long long)(b*SS + s))*512 + sub*64);
      const float* qp = &qs2[sub][0];
      const float* vp = &vsh[sub][0];
      float p_ = 0.f;
      #pragma unroll
      for (int i = 0; i < 8; ++i) {
        uint4 uv = up[i];
        int e = i*8;
        p_ = fmaf(vp[e+0], tanh_fast(qp[e+0] + bc(uv.x << 16)), p_);
        p_ = fmaf(vp[e+1], tanh_fast(qp[e+1] + bc(uv.x & 0xffff0000u)), p_);
        p_ = fmaf(vp[e+2], tanh_fast(qp[e+2] + bc(uv.y << 16)), p_);
        p_ = fmaf(vp[e+3], tanh_fast(qp[e+3] + bc(uv.y & 0xffff0000u)), p_);
        p_ = fmaf(vp[e+4], tanh_fast(qp[e+4] + bc(uv.z << 16)), p_);
        p_ = fmaf(vp[e+5], tanh_fast(qp[e+5] + bc(uv.z & 0xffff0000u)), p_);
        p_ = fmaf(vp[e+6], tanh_fast(qp[e+6] + bc(uv.w << 16)), p_);
        p_ = fmaf(vp[e+7], tanh_fast(qp[e+7] + bc(uv.w & 0xffff0000u)), p_);
      }
      p_ += __shfl_xor(p_, 1);
      p_ += __shfl_xor(p_, 2);
      p_ += __shfl_xor(p_, 4);
      if (sub == 0) sc[s] = p_ + bvp[0];
    }
    __syncthreads();

    if (tid < 64) {
      float x = sc[tid], mx = x;
      #pragma unroll
      for (int off = 32; off; off >>= 1) mx = fmaxf(mx, __shfl_xor(mx, off));
      float e = __expf(x - mx), sm = e;
      #pragma unroll
      for (int off = 32; off; off >>= 1) sm += __shfl_xor(sm, off);
      float w_ = e * frcp(sm);
      sw[tid] = w_;
      attn_out[((long long)b*TT + t)*SS + tid] = w_;
    }
    __syncthreads();

    {
      float a = 0.f;
      const unsigned short* ep = encbf + (long long)b*SS*512 + tid;
      #pragma unroll 8
      for (int s = 0; s < SS; ++s)
        a = fmaf(sw[s], b2f(ep[s*512]), a);
      ctxbf[b*512 + tid] = f2b(a);
    }
    __syncthreads();   // all ctx stores drained (vmcnt(0) before barrier)
    if (tid == 0)
      __hip_atomic_fetch_add(&flags[t], 1, __ATOMIC_RELEASE, __HIP_MEMORY_SCOPE_AGENT);
    return;
  }

  // ================= gates role, j0 = (bid-64)*32 =================
  const int blk = bid - 64;
  const int n0 = blk * 96, j0 = blk * 32;

  // wait for all 64 attn blocks (ctx ready)
  if (tid == 0) {
    while (__hip_atomic_load(&flags[t], __ATOMIC_ACQUIRE, __HIP_MEMORY_SCOPE_AGENT) < 64)
      __builtin_amdgcn_s_sleep(2);
  }
  __syncthreads();
  __threadfence();   // belt-and-suspenders acquire for all threads

  const int wl4 = w & 3;
  const int wr = wl4 >> 1, wc = wl4 & 1;

  f32x4 acc2[2][3];
  #pragma unroll
  for (int i = 0; i < 2; i++)
    #pragma unroll
    for (int j = 0; j < 3; j++) acc2[i][j] = (f32x4){0.f, 0.f, 0.f, 0.f};

  for (int k0 = 0; k0 < HH; k0 += 32) {
    __syncthreads();
    #pragma unroll
    for (int q = 0; q < 3; ++q) {
      int idx = tid + q*512;                    // 0..1535, use <1280
      if (idx < 256) {
        int r = idx >> 2, c8 = (idx & 3) * 8;
        GLDS(ctxbf + (long long)r*HH + k0 + c8, As + r*32 + c8);
      } else if (idx < 512) {
        int i2 = idx - 256, r = i2 >> 2, c8 = (i2 & 3) * 8;
        GLDS(hbf_r + (long long)r*HH + k0 + c8, Hs + r*32 + c8);
      } else if (idx < 896) {
        int i2 = idx - 512, r = i2 >> 2, c8 = (i2 & 3) * 8;
        GLDS(wihc3bf + (long long)(n0 + r)*HH + k0 + c8, Bs + r*32 + c8);
      } else if (idx < 1280) {
        int i2 = idx - 896, r = i2 >> 2, c8 = (i2 & 3) * 8;
        GLDS(whh3bf + (long long)(n0 + r)*HH + k0 + c8, Cs + r*32 + c8);
      }
    }
    __syncthreads();

    // waves 0-3: gic (ctx x wihc3);  waves 4-7: gh (h x whh3)
    const unsigned short* Ap = (w < 4) ? As : Hs;
    const unsigned short* Bp = (w < 4) ? Bs : Cs;
    bf16x8 a[2], b[3];
    #pragma unroll
    for (int mi = 0; mi < 2; mi++)
      a[mi] = *(const bf16x8*)&Ap[(wr*32 + mi*16 + (l & 15))*32 + (l >> 4)*8];
    #pragma unroll
    for (int ni = 0; ni < 3; ni++)
      b[ni] = *(const bf16x8*)&Bp[(wc*48 + ni*16 + (l & 15))*32 + (l >> 4)*8];
    #pragma unroll
    for (int mi = 0; mi < 2; mi++)
      #pragma unroll
      for (int ni = 0; ni < 3; ni++)
        acc2[mi][ni] = __builtin_amdgcn_mfma_f32_16x16x32_bf16(a[mi], b[ni], acc2[mi][ni], 0, 0, 0);
  }

  // prefetch Wa k-slice for the q-partial pass (overlaps epilogue)
  if (!last) {
    #pragma unroll
    for (int q = 0; q < 4; ++q) {
      int idx = tid + q*512;                    // 0..2047
      int r = idx >> 2, c8 = (idx & 3) * 8;
      GLDS(wabf + (long long)r*HH + j0 + c8, Was + r*32 + c8);
    }
  }

  {
    float* dst = (w < 4) ? gl : hl;
    #pragma unroll
    for (int mi = 0; mi < 2; mi++)
      #pragma unroll
      for (int ni = 0; ni < 3; ni++) {
        int col = wc*48 + ni*16 + (l & 15);
        #pragma unroll
        for (int r2 = 0; r2 < 4; r2++) {
          int row = wr*32 + mi*16 + (l >> 4)*4 + r2;
          dst[row*100 + col] = acc2[mi][ni][r2];
        }
      }
  }
  __syncthreads();

  // gates: 2048 (b, jj) pairs -> h_new
  for (int i = tid; i < 2048; i += 512) {
    const int b = i >> 5, jj = i & 31, j = j0 + jj;
    float gcr = gl[b*100 + jj*3 + 0];
    float gcz = gl[b*100 + jj*3 + 1];
    float gcn = gl[b*100 + jj*3 + 2];
    float ghr = hl[b*100 + jj*3 + 0] + bcat[512 + j];
    float ghz = hl[b*100 + jj*3 + 1] + bcat[1024 + j];
    float ghn = hl[b*100 + jj*3 + 2] + bcat[1536 + j];
    const long long gb = ((long long)t*BB + b)*H3 + j;
    float gir = b2f(giembbf[gb]);
    float giz = b2f(giembbf[gb + 512]);
    float gin = b2f(giembbf[gb + 1024]);
    float r = sigm(gir + gcr + ghr);
    float z = sigm(giz + gcz + ghz);
    float n = tanh_fast(gin + gcn + r * ghn);
    float hold = h32_r[b*512 + j];
    float hn = (1.f - z) * n + z * hold;
    h32_w[b*512 + j] = hn;
    unsigned short hb = f2b(hn);
    hbf_w[b*512 + j] = hb;
    hsall[((long long)b*TT + t)*512 + j] = hb;
    hnewp[b*40 + jj] = hb;
    if (t == TT - 1) out_ht[b*512 + j] = hn;
  }
  __syncthreads();

  // q-partial: qPart[blk][b][n] = h_new[b][kslice] . Wa[n][kslice]  (K=32)
  if (!last) {
    f32x4 qa[4][4];
    #pragma unroll
    for (int mi = 0; mi < 4; mi++)
      #pragma unroll
      for (int ni = 0; ni < 4; ni++) qa[mi][ni] = (f32x4){0.f, 0.f, 0.f, 0.f};

    bf16x8 a[4];
    #pragma unroll
    for (int mi = 0; mi < 4; mi++)
      a[mi] = *(const bf16x8*)&hnewp[(mi*16 + (l & 15))*40 + (l >> 4)*8];
    #pragma unroll
    for (int ni = 0; ni < 4; ni++) {
      bf16x8 bfr = *(const bf16x8*)&Was[(w*64 + ni*16 + (l & 15))*32 + (l >> 4)*8];
      #pragma unroll
      for (int mi = 0; mi < 4; mi++)
        qa[mi][ni] = __builtin_amdgcn_mfma_f32_16x16x32_bf16(a[mi], bfr, qa[mi][ni], 0, 0, 0);
    }

    float* qp = qPart + (long long)blk * 32768;
    #pragma unroll
    for (int mi = 0; mi < 4; mi++)
      #pragma unroll
      for (int ni = 0; ni < 4; ni++) {
        int col = w*64 + ni*16 + (l & 15);
        #pragma unroll
        for (int r2 = 0; r2 < 4; r2++) {
          int row = mi*16 + (l >> 4)*4 + r2;
          qp[row*512 + col] = qa[mi][ni][r2];
        }
      }
  }
}

// ---------------------------------------------------------------------------
// In-place log-softmax, register-resident: one read pass, one write pass.
// ---------------------------------------------------------------------------
__global__ __launch_bounds__(1024) void logsoftmax_kernel(float* __restrict__ lp)
{
  float4* p4 = (float4*)(lp + (long long)blockIdx.x * VV);
  const int tid = threadIdx.x;
  float4 x[8];
  float m = -1e30f, s = 0.f;
  #pragma unroll
  for (int i = 0; i < 8; ++i) {
    int v = tid + i*1024;
    if (v < 8000) {
      float4 xx = p4[v];
      x[i] = xx;
      float mx = fmaxf(fmaxf(xx.x, xx.y), fmaxf(xx.z, xx.w));
      float e = __expf(xx.x - mx) + __expf(xx.y - mx) + __expf(xx.z - mx) + __expf(xx.w - mx);
      if (mx > m) { s = s * __expf(m - mx) + e; m = mx; }
      else        { s += e * __expf(mx - m); }
    }
  }
  #pragma unroll
  for (int off = 32; off; off >>= 1) {
    float m2 = __shfl_xor(m, off), s2 = __shfl_xor(s, off);
    float mm = fmaxf(m, m2);
    s = s * __expf(m - mm) + s2 * __expf(m2 - mm);
    m = mm;
  }
  __shared__ float rm[16], rs[16];
  if ((tid & 63) == 0) { rm[tid >> 6] = m; rs[tid >> 6] = s; }
  __syncthreads();
  float M = rm[0], S = rs[0];
  #pragma unroll
  for (int i = 1; i < 16; ++i) {
    float m2 = rm[i], s2 = rs[i];
    float mm = fmaxf(M, m2);
    S = S * __expf(M - mm) + s2 * __expf(m2 - mm);
    M = mm;
  }
  const float L = M + logf(S);
  #pragma unroll
  for (int i = 0; i < 8; ++i) {
    int v = tid + i*1024;
    if (v < 8000) {
      float4 xx = x[i];
      xx.x -= L; xx.y -= L; xx.z -= L; xx.w -= L;
      p4[v] = xx;
    }
  }
}

// ---------------------------------------------------------------------------
extern "C" void kernel_launch(void* const* d_in, const int* in_sizes, int n_in,
                              void* d_out, int out_size, void* d_ws, size_t ws_size,
                              hipStream_t stream)
{
  const float* enc   = (const float*)d_in[0];
  const float* eh    = (const float*)d_in[1];
  const int*   tgt   = (const int*)  d_in[2];
  const float* emb   = (const float*)d_in[3];
  const float* Wa    = (const float*)d_in[4];
  const float* ba    = (const float*)d_in[5];
  const float* Ua    = (const float*)d_in[6];
  const float* bu    = (const float*)d_in[7];
  const float* Va    = (const float*)d_in[8];
  const float* bvp   = (const float*)d_in[9];
  const float* W_ih  = (const float*)d_in[10];
  const float* W_hh  = (const float*)d_in[11];
  const float* b_ih  = (const float*)d_in[12];
  const float* b_hh  = (const float*)d_in[13];
  const float* W_out = (const float*)d_in[14];
  const float* b_out = (const float*)d_in[15];

  float* out = (float*)d_out;
  float* ws  = (float*)d_ws;

  unsigned short* giembbf = (unsigned short*)(ws + WS_GIEMBBF);
  unsigned short* ukbf    = (unsigned short*)(ws + WS_UKBF);
  unsigned short* encbf   = (unsigned short*)(ws + WS_ENCBF);
  unsigned short* embbf   = (unsigned short*)(ws + WS_EMBBF);
  unsigned short* wcatbf  = (unsigned short*)(ws + WS_WCATBF);
  unsigned short* wihc3bf = (unsigned short*)(ws + WS_WIHC3);
  unsigned short* wihebf  = (unsigned short*)(ws + WS_WIHE);
  unsigned short* uabf    = (unsigned short*)(ws + WS_UABF);
  unsigned short* whh3bf  = (unsigned short*)(ws + WS_WHH3);
  float* bcat  = ws + WS_BCAT;
  float* qbuf  = ws + WS_QBUF;
  float* qPart = ws + WS_QPART;
  unsigned short* ctxbf = (unsigned short*)(ws + WS_CTXBF);
  float* h320 = ws + WS_H32;
  float* h321 = h320 + BB*HH;
  unsigned short* hbf0 = (unsigned short*)(ws + WS_HBF);
  unsigned short* hbf1 = hbf0 + BB*HH;
  unsigned short* hsall = (unsigned short*)(ws + WS_HSALL);
  int* flags = (int*)(ws + WS_FLAGS);
  unsigned short* wbf   = (unsigned short*)ws;   // aliases dead region post-recurrence

  float* attn_out = out + OUT_ATT;
  float* out_ht   = out + OUT_HT;

  // ---- prep ----
  hipMemsetAsync(flags, 0, TT * sizeof(int), stream);
  build_wcat_kernel<<<dim3(4096), dim3(256), 0, stream>>>(Wa, W_hh, ba, b_hh, wcatbf, bcat);
  build_g3_kernel<<<dim3(3072), dim3(256), 0, stream>>>(W_ih, wihc3bf, 1024, 512);
  build_g3_kernel<<<dim3(3072), dim3(256), 0, stream>>>(W_hh, whh3bf, 512, 0);
  build_wihe_kernel<<<dim3(3072), dim3(256), 0, stream>>>(W_ih, wihebf);
  cvt_f2b_kernel<<<dim3(256), dim3(256), 0, stream>>>(Ua, uabf, (long long)HH*HH);
  cvt_f2b_kernel<<<dim3(2048), dim3(256), 0, stream>>>(enc, encbf, (long long)BB*SS*HH);
  build_embbf_kernel<<<dim3(4096), dim3(256), 0, stream>>>(emb, tgt, embbf);
  hinit_kernel<<<dim3(128), dim3(256), 0, stream>>>(eh, hbf0, h320);

  // Uk (bf16 out) and GiEmb (bf16 out) via MFMA
  mfma_nt<1><<<dim3(4, 32), dim3(256), 0, stream>>>(encbf, uabf, bu, (void*)ukbf, (long long)HH);
  mfma_nt<1><<<dim3(12, 32), dim3(256), 0, stream>>>(embbf, wihebf, b_ih, (void*)giembbf, (long long)H3);

  // q(0) = h0 @ Wa^T (no bias; attn adds bcat)
  qinit_mfma<<<dim3(4), dim3(256), 0, stream>>>(hbf0, wcatbf, qbuf);

  // ---- recurrence: 1 launch/step ----
  for (int t = 0; t < TT; ++t) {
    const unsigned short* hr  = (t & 1) ? hbf1 : hbf0;
    const float*          h32r = (t & 1) ? h321 : h320;
    unsigned short*       hw  = (t & 1) ? hbf0 : hbf1;
    float*                h32w = (t & 1) ? h320 : h321;
    step_fused<<<dim3(80), dim3(512), 0, stream>>>(t, (t == 0) ? 1 : 0,
        (t == TT - 1) ? 1 : 0, qbuf, qPart, bcat, ukbf, encbf, Va, bvp,
        ctxbf, attn_out, hr, wihc3bf, whh3bf, wcatbf, giembbf,
        h32r, h32w, hw, hsall, out_ht, flags);
  }

  // ---- output projection + log-softmax ----
  cvt_f2b_kernel<<<dim3(16000), dim3(256), 0, stream>>>(W_out, wbf, (long long)VV*HH);
  mfma_nt<0><<<dim3(250, 32), dim3(256), 0, stream>>>(hsall, wbf, b_out, (void*)out, (long long)VV);
  logsoftmax_kernel<<<dim3(4096), dim3(1024), 0, stream>>>(out);
}

// Round 13
// 2155.664 us; speedup vs baseline: 1.0736x; 1.0736x over previous
//
#include <hip/hip_runtime.h>
#include <math.h>

#define HH 512
#define VV 32000
#define BB 64
#define SS 64
#define TT 64
#define H3 1536

// ---- workspace layout (float offsets); everything below WS_HSALL is dead
// after the recurrence, so wbf (32000*512 ushort = 8,192,000 f) aliases [0,8192000). ----
#define WS_GIEMBBF 0LL          // 4096*1536 ushort
#define WS_UKBF    3145728LL    // 4096*512 ushort
#define WS_ENCBF   4194304LL    // 4096*512 ushort
#define WS_EMBBF   5242880LL    // 4096*512 ushort
#define WS_WCATBF  6291456LL    // 2048*512 ushort (rows 0..511 = Wa bf16)
#define WS_WIHC3   6815744LL    // 1536*512 ushort (rows j*3+g, ctx half of W_ih)
#define WS_WIHE    7208960LL    // 1536*512 ushort (emb half of W_ih)
#define WS_UABF    7602176LL    // 512*512 ushort
#define WS_WHH3    7733248LL    // 1536*512 ushort (rows j*3+g of W_hh)
#define WS_BCAT    8126464LL    // 2048 f
#define WS_QBUF    8128512LL    // 64*512 f   (q for t=0, no bias)
#define WS_QPART   8161280LL    // 16*64*512 f (q partials)
#define WS_CTXBF   8685568LL    // 64*512 ushort
#define WS_H32     8701952LL    // 2 x 64*512 f
#define WS_HBF     8767488LL    // 2 x 64*512 ushort
#define WS_HSALL   8800256LL    // 4096*512 ushort (rows b*T+t) -- LIVE after recurrence
// end 9,848,832 f = 39.4 MB

// output layout (floats)
#define OUT_HT  ((long long)BB*TT*VV)
#define OUT_ATT (OUT_HT + (long long)BB*HH)

typedef __attribute__((ext_vector_type(8))) short bf16x8;
typedef __attribute__((ext_vector_type(4))) float f32x4;

__device__ inline unsigned short f2b(float x) {
  unsigned u = __builtin_bit_cast(unsigned, x);
  unsigned r = (u + 0x7FFF + ((u >> 16) & 1)) >> 16;
  return (unsigned short)r;
}
__device__ inline float bc(unsigned u) { return __builtin_bit_cast(float, u); }
__device__ inline float b2f(unsigned short h) { return bc(((unsigned)h) << 16); }
__device__ inline float frcp(float x) { return __builtin_amdgcn_rcpf(x); }
__device__ inline float tanh_fast(float x) { return 1.f - 2.f * frcp(__expf(2.f * x) + 1.f); }
__device__ inline float sigm(float x) { return frcp(1.f + __expf(-x)); }

#define GLDS(gp, lp) __builtin_amdgcn_global_load_lds( \
    (const __attribute__((address_space(1))) void*)(gp), \
    (__attribute__((address_space(3))) void*)(lp), 16, 0, 0)

// ---------------------------------------------------------------------------
// prep kernels
// ---------------------------------------------------------------------------
__global__ __launch_bounds__(256) void build_wcat_kernel(const float* __restrict__ Wa,
    const float* __restrict__ Whh, const float* __restrict__ ba,
    const float* __restrict__ bhh, unsigned short* __restrict__ wcatbf,
    float* __restrict__ bcat)
{
  long long i = (long long)blockIdx.x * 256 + threadIdx.x;   // 2048*512
  int j = (int)(i >> 9), k = (int)(i & 511);
  float v = (j < HH) ? Wa[(long long)j*HH + k] : Whh[(long long)(j - HH)*HH + k];
  wcatbf[i] = f2b(v);
  if (i < 2048) bcat[i] = (i < HH) ? ba[i] : bhh[i - HH];
}

// o[(j*3+g)][k] = Wsrc[g*512+j][ofs+k]; Wsrc row stride = ld
__global__ __launch_bounds__(256) void build_g3_kernel(const float* __restrict__ Wsrc,
    unsigned short* __restrict__ o, int ld, int ofs)
{
  long long i = (long long)blockIdx.x * 256 + threadIdx.x;   // 1536*512
  int rp = (int)(i >> 9), k = (int)(i & 511);
  int j = rp / 3, g = rp - j * 3;
  o[i] = f2b(Wsrc[((long long)(g*512 + j))*ld + ofs + k]);
}

// wihebf[j][k] = W_ih[j][k]  (emb half)
__global__ __launch_bounds__(256) void build_wihe_kernel(const float* __restrict__ W_ih,
    unsigned short* __restrict__ o)
{
  long long i = (long long)blockIdx.x * 256 + threadIdx.x;   // 1536*512
  o[i] = f2b(W_ih[(long long)(i >> 9)*1024 + (i & 511)]);
}

__global__ __launch_bounds__(256) void cvt_f2b_kernel(const float* __restrict__ in,
    unsigned short* __restrict__ outp, long long n)
{
  long long i = ((long long)blockIdx.x * 256 + threadIdx.x) * 4;
  if (i >= n) return;
  float4 v = *(const float4*)(in + i);
  ushort4 r = { f2b(v.x), f2b(v.y), f2b(v.z), f2b(v.w) };
  *(ushort4*)(outp + i) = r;
}

// embbf row m = t*64+b  <-  emb[tok(b,t)]
__global__ __launch_bounds__(256) void build_embbf_kernel(const float* __restrict__ emb,
    const int* __restrict__ tgt, unsigned short* __restrict__ embbf)
{
  const int m = blockIdx.x, t = m >> 6, b = m & 63;
  const int tk = (t == 0) ? 0 : tgt[b*TT + t - 1];
  const float* src = emb + (long long)tk*HH;
  unsigned short* dst = embbf + (long long)m*HH;
  const int i = threadIdx.x;
  dst[i] = f2b(src[i]);
  dst[i + 256] = f2b(src[i + 256]);
}

__global__ __launch_bounds__(256) void hinit_kernel(const float* __restrict__ eh,
    unsigned short* __restrict__ hbf0, float* __restrict__ h320)
{
  int i = blockIdx.x * 256 + threadIdx.x;   // 32768
  float v = eh[i];
  hbf0[i] = f2b(v);
  h320[i] = v;
}

// ---------------------------------------------------------------------------
// Generic NT MFMA GEMM: C[m][n] = A[m,:512].B[n,:512] + bias[n]
// ---------------------------------------------------------------------------
template<int OUTBF>
__global__ __launch_bounds__(256) void mfma_nt(const unsigned short* __restrict__ A,
    const unsigned short* __restrict__ Bw, const float* __restrict__ bias,
    void* __restrict__ Cv, long long ldc)
{
  __shared__ unsigned short As[128*32];
  __shared__ unsigned short Bs[128*32];
  const int tid = threadIdx.x;
  const int w = tid >> 6, l = tid & 63;
  const int m0 = blockIdx.y * 128, n0 = blockIdx.x * 128;
  const int wr = w >> 1, wc = w & 1;

  f32x4 acc[4][4];
  #pragma unroll
  for (int i = 0; i < 4; i++)
    #pragma unroll
    for (int j = 0; j < 4; j++) acc[i][j] = (f32x4){0.f, 0.f, 0.f, 0.f};

  const int srow = l >> 2;
  const int scol = (l & 3) * 8;

  for (int k0 = 0; k0 < HH; k0 += 32) {
    __syncthreads();
    #pragma unroll
    for (int q = 0; q < 2; ++q) {
      int r = w*32 + q*16 + srow;
      GLDS(A  + (long long)(m0 + r)*HH + k0 + scol, As + r*32 + scol);
      GLDS(Bw + (long long)(n0 + r)*HH + k0 + scol, Bs + r*32 + scol);
    }
    __syncthreads();

    bf16x8 a[4], b[4];
    #pragma unroll
    for (int mi = 0; mi < 4; mi++)
      a[mi] = *(const bf16x8*)&As[(wr*64 + mi*16 + (l & 15))*32 + (l >> 4)*8];
    #pragma unroll
    for (int ni = 0; ni < 4; ni++)
      b[ni] = *(const bf16x8*)&Bs[(wc*64 + ni*16 + (l & 15))*32 + (l >> 4)*8];
    #pragma unroll
    for (int mi = 0; mi < 4; mi++)
      #pragma unroll
      for (int ni = 0; ni < 4; ni++)
        acc[mi][ni] = __builtin_amdgcn_mfma_f32_16x16x32_bf16(a[mi], b[ni], acc[mi][ni], 0, 0, 0);
  }

  #pragma unroll
  for (int mi = 0; mi < 4; mi++) {
    #pragma unroll
    for (int ni = 0; ni < 4; ni++) {
      int col = n0 + wc*64 + ni*16 + (l & 15);
      float bb = bias[col];
      #pragma unroll
      for (int r2 = 0; r2 < 4; r2++) {
        int row = m0 + wr*64 + mi*16 + (l >> 4)*4 + r2;
        float v = acc[mi][ni][r2] + bb;
        if (OUTBF) ((unsigned short*)Cv)[(long long)row*ldc + col] = f2b(v);
        else       ((float*)Cv)[(long long)row*ldc + col] = v;
      }
    }
  }
}

// ---------------------------------------------------------------------------
// qinit: qbuf[64][512] = h0 @ Wa^T (no bias). grid 4, 256 thr.
// ---------------------------------------------------------------------------
__global__ __launch_bounds__(256) void qinit_mfma(
    const unsigned short* __restrict__ hbf_r, const unsigned short* __restrict__ wabf,
    float* __restrict__ qbuf)
{
  __shared__ unsigned short As[64*32];
  __shared__ unsigned short Bs[128*32];
  const int tid = threadIdx.x;
  const int w = tid >> 6, l = tid & 63;
  const int n0 = blockIdx.x * 128;
  const int wr = w >> 1, wc = w & 1;

  f32x4 acc[2][4];
  #pragma unroll
  for (int i = 0; i < 2; i++)
    #pragma unroll
    for (int j = 0; j < 4; j++) acc[i][j] = (f32x4){0.f, 0.f, 0.f, 0.f};

  const int ar = tid >> 2;
  const int ac8 = (tid & 3) * 8;

  for (int k0 = 0; k0 < HH; k0 += 32) {
    __syncthreads();
    GLDS(hbf_r + (long long)ar*HH + k0 + ac8, As + ar*32 + ac8);
    #pragma unroll
    for (int q = 0; q < 2; ++q) {
      int r = q*64 + ar;
      GLDS(wabf + (long long)(n0 + r)*HH + k0 + ac8, Bs + r*32 + ac8);
    }
    __syncthreads();

    bf16x8 a[2], b[4];
    #pragma unroll
    for (int mi = 0; mi < 2; mi++)
      a[mi] = *(const bf16x8*)&As[(wr*32 + mi*16 + (l & 15))*32 + (l >> 4)*8];
    #pragma unroll
    for (int ni = 0; ni < 4; ni++)
      b[ni] = *(const bf16x8*)&Bs[(wc*64 + ni*16 + (l & 15))*32 + (l >> 4)*8];
    #pragma unroll
    for (int mi = 0; mi < 2; mi++)
      #pragma unroll
      for (int ni = 0; ni < 4; ni++)
        acc[mi][ni] = __builtin_amdgcn_mfma_f32_16x16x32_bf16(a[mi], b[ni], acc[mi][ni], 0, 0, 0);
  }

  #pragma unroll
  for (int mi = 0; mi < 2; mi++) {
    #pragma unroll
    for (int ni = 0; ni < 4; ni++) {
      int col = n0 + wc*64 + ni*16 + (l & 15);
      #pragma unroll
      for (int r2 = 0; r2 < 4; r2++) {
        int row = wr*32 + mi*16 + (l >> 4)*4 + r2;
        qbuf[(long long)row*512 + col] = acc[mi][ni][r2];
      }
    }
  }
}

// ---------------------------------------------------------------------------
// attn for batch b = blockIdx.x, 512 thr. q = bcat + (qbuf | sum of 16 qPart).
// ---------------------------------------------------------------------------
__global__ __launch_bounds__(512) void attn_kernel(int t, int first,
    const float* __restrict__ qbuf, const float* __restrict__ qPart,
    const float* __restrict__ bcat, const unsigned short* __restrict__ ukbf,
    const unsigned short* __restrict__ encbf, const float* __restrict__ Va,
    const float* __restrict__ bvp,
    unsigned short* __restrict__ ctxbf, float* __restrict__ attn_out)
{
  const int b = blockIdx.x, tid = threadIdx.x;
  __shared__ float qs2[8][68];
  __shared__ float vsh[8][68];
  __shared__ float sc[SS], sw[SS];

  {
    const int c = tid;
    float q = bcat[c];
    if (first) {
      q += qbuf[(long long)b*512 + c];
    } else {
      #pragma unroll
      for (int i = 0; i < 16; ++i)
        q += qPart[(long long)i*32768 + b*512 + c];
    }
    qs2[c >> 6][c & 63] = q;
    vsh[c >> 6][c & 63] = Va[c];
  }
  __syncthreads();

  // scores: (s = tid>>3, sub = tid&7), 64 k each
  {
    const int s = tid >> 3, sub = tid & 7;
    const uint4* up = (const uint4*)(ukbf + ((long long)(b*SS + s))*512 + sub*64);
    const float* qp = &qs2[sub][0];
    const float* vp = &vsh[sub][0];
    float p_ = 0.f;
    #pragma unroll
    for (int i = 0; i < 8; ++i) {
      uint4 uv = up[i];
      int e = i*8;
      p_ = fmaf(vp[e+0], tanh_fast(qp[e+0] + bc(uv.x << 16)), p_);
      p_ = fmaf(vp[e+1], tanh_fast(qp[e+1] + bc(uv.x & 0xffff0000u)), p_);
      p_ = fmaf(vp[e+2], tanh_fast(qp[e+2] + bc(uv.y << 16)), p_);
      p_ = fmaf(vp[e+3], tanh_fast(qp[e+3] + bc(uv.y & 0xffff0000u)), p_);
      p_ = fmaf(vp[e+4], tanh_fast(qp[e+4] + bc(uv.z << 16)), p_);
      p_ = fmaf(vp[e+5], tanh_fast(qp[e+5] + bc(uv.z & 0xffff0000u)), p_);
      p_ = fmaf(vp[e+6], tanh_fast(qp[e+6] + bc(uv.w << 16)), p_);
      p_ = fmaf(vp[e+7], tanh_fast(qp[e+7] + bc(uv.w & 0xffff0000u)), p_);
    }
    p_ += __shfl_xor(p_, 1);
    p_ += __shfl_xor(p_, 2);
    p_ += __shfl_xor(p_, 4);
    if (sub == 0) sc[s] = p_ + bvp[0];
  }
  __syncthreads();

  if (tid < 64) {
    float x = sc[tid], mx = x;
    #pragma unroll
    for (int off = 32; off; off >>= 1) mx = fmaxf(mx, __shfl_xor(mx, off));
    float e = __expf(x - mx), sm = e;
    #pragma unroll
    for (int off = 32; off; off >>= 1) sm += __shfl_xor(sm, off);
    float w_ = e * frcp(sm);
    sw[tid] = w_;
    attn_out[((long long)b*TT + t)*SS + tid] = w_;
  }
  __syncthreads();

  {
    float a = 0.f;
    const unsigned short* ep = encbf + (long long)b*SS*512 + tid;
    #pragma unroll 8
    for (int s = 0; s < SS; ++s)
      a = fmaf(sw[s], b2f(ep[s*512]), a);
    ctxbf[b*512 + tid] = f2b(a);
  }
}

// ---------------------------------------------------------------------------
// gates_qgh: gh + gic (two gate-interleaved 64x96 MFMA GEMMs) + gates + h,
// then q-partial for step t+1: qPart[bid] = h_new[:, kslice] @ Wa[:, kslice]^T.
// grid 16 (j0 = kslice = blockIdx.x*32), 256 thr.
// ---------------------------------------------------------------------------
__global__ __launch_bounds__(256) void gates_qgh_mfma(int t, int last,
    const unsigned short* __restrict__ hbf_r, const unsigned short* __restrict__ ctxbf,
    const unsigned short* __restrict__ wihc3bf, const unsigned short* __restrict__ whh3bf,
    const unsigned short* __restrict__ wabf, const float* __restrict__ bcat,
    const unsigned short* __restrict__ giembbf,
    const float* __restrict__ h32_r, float* __restrict__ h32_w,
    unsigned short* __restrict__ hbf_w, unsigned short* __restrict__ hsall,
    float* __restrict__ out_ht, float* __restrict__ qPart)
{
  __shared__ unsigned short As[64*32];   // ctx tile
  __shared__ unsigned short Hs[64*32];   // h tile
  __shared__ unsigned short Bs[96*32];   // wihc3 rows
  __shared__ unsigned short Cs[96*32];   // whh3 rows
  __shared__ unsigned short Was[512*32]; // Wa k-slice (all 512 rows x 32 k)
  __shared__ unsigned short hnewp[64*40];// h_new slice, padded rows
  __shared__ float gl[64*100];           // gic [64][96] padded
  __shared__ float hl[64*100];           // gh  [64][96] padded
  const int tid = threadIdx.x;
  const int w = tid >> 6, l = tid & 63;
  const int n0 = blockIdx.x * 96, j0 = blockIdx.x * 32;
  const int wr = w >> 1, wc = w & 1;

  f32x4 accg[2][3], acch[2][3];
  #pragma unroll
  for (int i = 0; i < 2; i++)
    #pragma unroll
    for (int j = 0; j < 3; j++) {
      accg[i][j] = (f32x4){0.f, 0.f, 0.f, 0.f};
      acch[i][j] = (f32x4){0.f, 0.f, 0.f, 0.f};
    }

  for (int k0 = 0; k0 < HH; k0 += 32) {
    __syncthreads();
    #pragma unroll
    for (int q = 0; q < 5; ++q) {
      int idx = tid + q*256;                    // 0..1279
      if (idx < 256) {
        int r = idx >> 2, c8 = (idx & 3) * 8;
        GLDS(ctxbf + (long long)r*HH + k0 + c8, As + r*32 + c8);
      } else if (idx < 512) {
        int i2 = idx - 256, r = i2 >> 2, c8 = (i2 & 3) * 8;
        GLDS(hbf_r + (long long)r*HH + k0 + c8, Hs + r*32 + c8);
      } else if (idx < 896) {
        int i2 = idx - 512, r = i2 >> 2, c8 = (i2 & 3) * 8;
        GLDS(wihc3bf + (long long)(n0 + r)*HH + k0 + c8, Bs + r*32 + c8);
      } else {
        int i2 = idx - 896, r = i2 >> 2, c8 = (i2 & 3) * 8;
        GLDS(whh3bf + (long long)(n0 + r)*HH + k0 + c8, Cs + r*32 + c8);
      }
    }
    __syncthreads();

    bf16x8 ag[2], ah[2], bg[3], bh[3];
    #pragma unroll
    for (int mi = 0; mi < 2; mi++) {
      ag[mi] = *(const bf16x8*)&As[(wr*32 + mi*16 + (l & 15))*32 + (l >> 4)*8];
      ah[mi] = *(const bf16x8*)&Hs[(wr*32 + mi*16 + (l & 15))*32 + (l >> 4)*8];
    }
    #pragma unroll
    for (int ni = 0; ni < 3; ni++) {
      bg[ni] = *(const bf16x8*)&Bs[(wc*48 + ni*16 + (l & 15))*32 + (l >> 4)*8];
      bh[ni] = *(const bf16x8*)&Cs[(wc*48 + ni*16 + (l & 15))*32 + (l >> 4)*8];
    }
    #pragma unroll
    for (int mi = 0; mi < 2; mi++)
      #pragma unroll
      for (int ni = 0; ni < 3; ni++) {
        accg[mi][ni] = __builtin_amdgcn_mfma_f32_16x16x32_bf16(ag[mi], bg[ni], accg[mi][ni], 0, 0, 0);
        acch[mi][ni] = __builtin_amdgcn_mfma_f32_16x16x32_bf16(ah[mi], bh[ni], acch[mi][ni], 0, 0, 0);
      }
  }

  // prefetch Wa k-slice for the q-partial pass (overlaps gl/hl + gates)
  if (!last) {
    #pragma unroll
    for (int q = 0; q < 8; ++q) {
      int idx = tid + q*256;                    // 0..2047
      int r = idx >> 2, c8 = (idx & 3) * 8;
      GLDS(wabf + (long long)r*HH + j0 + c8, Was + r*32 + c8);
    }
  }

  #pragma unroll
  for (int mi = 0; mi < 2; mi++)
    #pragma unroll
    for (int ni = 0; ni < 3; ni++) {
      int col = wc*48 + ni*16 + (l & 15);
      #pragma unroll
      for (int r2 = 0; r2 < 4; r2++) {
        int row = wr*32 + mi*16 + (l >> 4)*4 + r2;
        gl[row*100 + col] = accg[mi][ni][r2];
        hl[row*100 + col] = acch[mi][ni][r2];
      }
    }
  __syncthreads();

  // gates: 2048 (b, jj) pairs -> h_new
  for (int i = tid; i < 2048; i += 256) {
    const int b = i >> 5, jj = i & 31, j = j0 + jj;
    float gcr = gl[b*100 + jj*3 + 0];
    float gcz = gl[b*100 + jj*3 + 1];
    float gcn = gl[b*100 + jj*3 + 2];
    float ghr = hl[b*100 + jj*3 + 0] + bcat[512 + j];
    float ghz = hl[b*100 + jj*3 + 1] + bcat[1024 + j];
    float ghn = hl[b*100 + jj*3 + 2] + bcat[1536 + j];
    const long long gb = ((long long)t*BB + b)*H3 + j;
    float gir = b2f(giembbf[gb]);
    float giz = b2f(giembbf[gb + 512]);
    float gin = b2f(giembbf[gb + 1024]);
    float r = sigm(gir + gcr + ghr);
    float z = sigm(giz + gcz + ghz);
    float n = tanh_fast(gin + gcn + r * ghn);
    float hold = h32_r[b*512 + j];
    float hn = (1.f - z) * n + z * hold;
    h32_w[b*512 + j] = hn;
    unsigned short hb = f2b(hn);
    hbf_w[b*512 + j] = hb;
    hsall[((long long)b*TT + t)*512 + j] = hb;
    hnewp[b*40 + jj] = hb;
    if (t == TT - 1) out_ht[b*512 + j] = hn;
  }
  __syncthreads();

  // q-partial: qPart[bid][b][n] = h_new[b][kslice] . Wa[n][kslice]  (K=32, one MFMA)
  if (!last) {
    f32x4 qa[4][8];
    #pragma unroll
    for (int mi = 0; mi < 4; mi++)
      #pragma unroll
      for (int ni = 0; ni < 8; ni++) qa[mi][ni] = (f32x4){0.f, 0.f, 0.f, 0.f};

    bf16x8 a[4];
    #pragma unroll
    for (int mi = 0; mi < 4; mi++)
      a[mi] = *(const bf16x8*)&hnewp[(mi*16 + (l & 15))*40 + (l >> 4)*8];
    #pragma unroll
    for (int ni = 0; ni < 8; ni++) {
      bf16x8 bfr = *(const bf16x8*)&Was[(w*128 + ni*16 + (l & 15))*32 + (l >> 4)*8];
      #pragma unroll
      for (int mi = 0; mi < 4; mi++)
        qa[mi][ni] = __builtin_amdgcn_mfma_f32_16x16x32_bf16(a[mi], bfr, qa[mi][ni], 0, 0, 0);
    }

    float* qp = qPart + (long long)blockIdx.x * 32768;
    #pragma unroll
    for (int mi = 0; mi < 4; mi++)
      #pragma unroll
      for (int ni = 0; ni < 8; ni++) {
        int col = w*128 + ni*16 + (l & 15);
        #pragma unroll
        for (int r2 = 0; r2 < 4; r2++) {
          int row = mi*16 + (l >> 4)*4 + r2;
          qp[row*512 + col] = qa[mi][ni][r2];
        }
      }
  }
}

// ---------------------------------------------------------------------------
// In-place log-softmax, register-resident: one read pass, one write pass.
// ---------------------------------------------------------------------------
__global__ __launch_bounds__(1024) void logsoftmax_kernel(float* __restrict__ lp)
{
  float4* p4 = (float4*)(lp + (long long)blockIdx.x * VV);
  const int tid = threadIdx.x;
  float4 x[8];
  float m = -1e30f, s = 0.f;
  #pragma unroll
  for (int i = 0; i < 8; ++i) {
    int v = tid + i*1024;
    if (v < 8000) {
      float4 xx = p4[v];
      x[i] = xx;
      float mx = fmaxf(fmaxf(xx.x, xx.y), fmaxf(xx.z, xx.w));
      float e = __expf(xx.x - mx) + __expf(xx.y - mx) + __expf(xx.z - mx) + __expf(xx.w - mx);
      if (mx > m) { s = s * __expf(m - mx) + e; m = mx; }
      else        { s += e * __expf(mx - m); }
    }
  }
  #pragma unroll
  for (int off = 32; off; off >>= 1) {
    float m2 = __shfl_xor(m, off), s2 = __shfl_xor(s, off);
    float mm = fmaxf(m, m2);
    s = s * __expf(m - mm) + s2 * __expf(m2 - mm);
    m = mm;
  }
  __shared__ float rm[16], rs[16];
  if ((tid & 63) == 0) { rm[tid >> 6] = m; rs[tid >> 6] = s; }
  __syncthreads();
  float M = rm[0], S = rs[0];
  #pragma unroll
  for (int i = 1; i < 16; ++i) {
    float m2 = rm[i], s2 = rs[i];
    float mm = fmaxf(M, m2);
    S = S * __expf(M - mm) + s2 * __expf(m2 - mm);
    M = mm;
  }
  const float L = M + logf(S);
  #pragma unroll
  for (int i = 0; i < 8; ++i) {
    int v = tid + i*1024;
    if (v < 8000) {
      float4 xx = x[i];
      xx.x -= L; xx.y -= L; xx.z -= L; xx.w -= L;
      p4[v] = xx;
    }
  }
}

// ---------------------------------------------------------------------------
extern "C" void kernel_launch(void* const* d_in, const int* in_sizes, int n_in,
                              void* d_out, int out_size, void* d_ws, size_t ws_size,
                              hipStream_t stream)
{
  const float* enc   = (const float*)d_in[0];
  const float* eh    = (const float*)d_in[1];
  const int*   tgt   = (const int*)  d_in[2];
  const float* emb   = (const float*)d_in[3];
  const float* Wa    = (const float*)d_in[4];
  const float* ba    = (const float*)d_in[5];
  const float* Ua    = (const float*)d_in[6];
  const float* bu    = (const float*)d_in[7];
  const float* Va    = (const float*)d_in[8];
  const float* bvp   = (const float*)d_in[9];
  const float* W_ih  = (const float*)d_in[10];
  const float* W_hh  = (const float*)d_in[11];
  const float* b_ih  = (const float*)d_in[12];
  const float* b_hh  = (const float*)d_in[13];
  const float* W_out = (const float*)d_in[14];
  const float* b_out = (const float*)d_in[15];

  float* out = (float*)d_out;
  float* ws  = (float*)d_ws;

  unsigned short* giembbf = (unsigned short*)(ws + WS_GIEMBBF);
  unsigned short* ukbf    = (unsigned short*)(ws + WS_UKBF);
  unsigned short* encbf   = (unsigned short*)(ws + WS_ENCBF);
  unsigned short* embbf   = (unsigned short*)(ws + WS_EMBBF);
  unsigned short* wcatbf  = (unsigned short*)(ws + WS_WCATBF);
  unsigned short* wihc3bf = (unsigned short*)(ws + WS_WIHC3);
  unsigned short* wihebf  = (unsigned short*)(ws + WS_WIHE);
  unsigned short* uabf    = (unsigned short*)(ws + WS_UABF);
  unsigned short* whh3bf  = (unsigned short*)(ws + WS_WHH3);
  float* bcat  = ws + WS_BCAT;
  float* qbuf  = ws + WS_QBUF;
  float* qPart = ws + WS_QPART;
  unsigned short* ctxbf = (unsigned short*)(ws + WS_CTXBF);
  float* h320 = ws + WS_H32;
  float* h321 = h320 + BB*HH;
  unsigned short* hbf0 = (unsigned short*)(ws + WS_HBF);
  unsigned short* hbf1 = hbf0 + BB*HH;
  unsigned short* hsall = (unsigned short*)(ws + WS_HSALL);
  unsigned short* wbf   = (unsigned short*)ws;   // aliases dead region post-recurrence

  float* attn_out = out + OUT_ATT;
  float* out_ht   = out + OUT_HT;

  // ---- prep ----
  build_wcat_kernel<<<dim3(4096), dim3(256), 0, stream>>>(Wa, W_hh, ba, b_hh, wcatbf, bcat);
  build_g3_kernel<<<dim3(3072), dim3(256), 0, stream>>>(W_ih, wihc3bf, 1024, 512);
  build_g3_kernel<<<dim3(3072), dim3(256), 0, stream>>>(W_hh, whh3bf, 512, 0);
  build_wihe_kernel<<<dim3(3072), dim3(256), 0, stream>>>(W_ih, wihebf);
  cvt_f2b_kernel<<<dim3(256), dim3(256), 0, stream>>>(Ua, uabf, (long long)HH*HH);
  cvt_f2b_kernel<<<dim3(2048), dim3(256), 0, stream>>>(enc, encbf, (long long)BB*SS*HH);
  build_embbf_kernel<<<dim3(4096), dim3(256), 0, stream>>>(emb, tgt, embbf);
  hinit_kernel<<<dim3(128), dim3(256), 0, stream>>>(eh, hbf0, h320);

  // Uk (bf16 out) and GiEmb (bf16 out) via MFMA
  mfma_nt<1><<<dim3(4, 32), dim3(256), 0, stream>>>(encbf, uabf, bu, (void*)ukbf, (long long)HH);
  mfma_nt<1><<<dim3(12, 32), dim3(256), 0, stream>>>(embbf, wihebf, b_ih, (void*)giembbf, (long long)H3);

  // q(0) = h0 @ Wa^T (no bias; attn adds bcat)
  qinit_mfma<<<dim3(4), dim3(256), 0, stream>>>(hbf0, wcatbf, qbuf);

  // ---- recurrence: 2 launches/step ----
  for (int t = 0; t < TT; ++t) {
    const unsigned short* hr  = (t & 1) ? hbf1 : hbf0;
    const float*          h32r = (t & 1) ? h321 : h320;
    unsigned short*       hw  = (t & 1) ? hbf0 : hbf1;
    float*                h32w = (t & 1) ? h320 : h321;
    attn_kernel<<<dim3(64), dim3(512), 0, stream>>>(t, (t == 0) ? 1 : 0, qbuf, qPart,
        bcat, ukbf, encbf, Va, bvp, ctxbf, attn_out);
    gates_qgh_mfma<<<dim3(16), dim3(256), 0, stream>>>(t, (t == TT - 1) ? 1 : 0,
        hr, ctxbf, wihc3bf, whh3bf, wcatbf, bcat, giembbf,
        h32r, h32w, hw, hsall, out_ht, qPart);
  }

  // ---- output projection + log-softmax ----
  cvt_f2b_kernel<<<dim3(16000), dim3(256), 0, stream>>>(W_out, wbf, (long long)VV*HH);
  mfma_nt<0><<<dim3(250, 32), dim3(256), 0, stream>>>(hsall, wbf, b_out, (void*)out, (long long)VV);
  logsoftmax_kernel<<<dim3(4096), dim3(1024), 0, stream>>>(out);
}

// Round 14
// 2103.276 us; speedup vs baseline: 1.1003x; 1.0249x over previous
//
#include <hip/hip_runtime.h>
#include <math.h>

#define HH 512
#define VV 32000
#define BB 64
#define SS 64
#define TT 64
#define H3 1536

// ---- workspace layout (float offsets); everything below WS_HSALL is dead
// after the recurrence, so wbf (32000*512 ushort = 8,192,000 f) aliases [0,8192000). ----
#define WS_GIEMBBF 0LL          // 4096*1536 ushort
#define WS_UKBF    3145728LL    // 4096*512 ushort
#define WS_ENCBF   4194304LL    // 4096*512 ushort
#define WS_EMBBF   5242880LL    // 4096*512 ushort
#define WS_WCATBF  6291456LL    // 2048*512 ushort (rows 0..511 = Wa bf16)
#define WS_WIHC3   6815744LL    // 1536*512 ushort (rows j*3+g, ctx half of W_ih)
#define WS_WIHE    7208960LL    // 1536*512 ushort (emb half of W_ih)
#define WS_UABF    7602176LL    // 512*512 ushort
#define WS_WHH3    7733248LL    // 1536*512 ushort (rows j*3+g of W_hh)
#define WS_BCAT    8126464LL    // 2048 f
#define WS_QBUF    8128512LL    // 64*512 f   (q for t=0, no bias)
#define WS_QPART   8161280LL    // 16*64*512 f (q partials)
#define WS_CTXBF   8685568LL    // 64*512 ushort
#define WS_H32     8701952LL    // 2 x 64*512 f
#define WS_HBF     8767488LL    // 2 x 64*512 ushort
#define WS_HSALL   8800256LL    // 4096*512 ushort (rows b*T+t) -- LIVE after recurrence
// end 9,848,832 f = 39.4 MB

// output layout (floats)
#define OUT_HT  ((long long)BB*TT*VV)
#define OUT_ATT (OUT_HT + (long long)BB*HH)

// prep_all flat segment offsets (elements; every boundary is 1024-aligned)
#define P_WCAT  0LL          // 1,048,576 (first 262,144 from Wa, rest Whh)
#define P_WIHC3 1048576LL    // 786,432
#define P_WHH3  1835008LL    // 786,432
#define P_WIHE  2621440LL    // 786,432
#define P_UA    3407872LL    // 262,144
#define P_ENC   3670016LL    // 2,097,152
#define P_EMB   5767168LL    // 2,097,152
#define P_HINIT 7864320LL    // 32,768
#define P_BCAT  7897088LL    // 2,048
#define P_TOT   7899136LL    // = 7714 * 1024

typedef __attribute__((ext_vector_type(8))) short bf16x8;
typedef __attribute__((ext_vector_type(4))) float f32x4;

__device__ inline unsigned short f2b(float x) {
  unsigned u = __builtin_bit_cast(unsigned, x);
  unsigned r = (u + 0x7FFF + ((u >> 16) & 1)) >> 16;
  return (unsigned short)r;
}
__device__ inline float bc(unsigned u) { return __builtin_bit_cast(float, u); }
__device__ inline float b2f(unsigned short h) { return bc(((unsigned)h) << 16); }
__device__ inline float frcp(float x) { return __builtin_amdgcn_rcpf(x); }
__device__ inline float tanh_fast(float x) { return 1.f - 2.f * frcp(__expf(2.f * x) + 1.f); }
__device__ inline float sigm(float x) { return frcp(1.f + __expf(-x)); }

#define GLDS(gp, lp) __builtin_amdgcn_global_load_lds( \
    (const __attribute__((address_space(1))) void*)(gp), \
    (__attribute__((address_space(3))) void*)(lp), 16, 0, 0)

__device__ inline ushort4 cvt4(float4 v) {
  ushort4 r = { f2b(v.x), f2b(v.y), f2b(v.z), f2b(v.w) };
  return r;
}

// ---------------------------------------------------------------------------
// prep_all: every weight/activation conversion in ONE kernel.
// grid 7714 x 256; each thread converts 4 consecutive elements; every segment
// size is a multiple of 1024 so branches are block-uniform.
// ---------------------------------------------------------------------------
__global__ __launch_bounds__(256) void prep_all(
    const float* __restrict__ Wa, const float* __restrict__ Whh,
    const float* __restrict__ ba, const float* __restrict__ bhh,
    const float* __restrict__ W_ih, const float* __restrict__ Ua,
    const float* __restrict__ enc, const float* __restrict__ emb,
    const int* __restrict__ tgt, const float* __restrict__ eh,
    unsigned short* __restrict__ wcatbf, unsigned short* __restrict__ wihc3bf,
    unsigned short* __restrict__ whh3bf, unsigned short* __restrict__ wihebf,
    unsigned short* __restrict__ uabf, unsigned short* __restrict__ encbf,
    unsigned short* __restrict__ embbf, unsigned short* __restrict__ hbf0,
    float* __restrict__ h320, float* __restrict__ bcat)
{
  const long long base = (long long)blockIdx.x * 1024 + threadIdx.x * 4;

  if (base < P_WIHC3) {                                  // wcat: [Wa ; Whh] flat
    long long i = base - P_WCAT;
    float4 v = (i < 262144) ? *(const float4*)(Wa + i)
                            : *(const float4*)(Whh + (i - 262144));
    *(ushort4*)(wcatbf + i) = cvt4(v);
  } else if (base < P_WHH3) {                            // wihc3: (j*3+g) <- W_ih ctx half
    long long i = base - P_WIHC3;
    int rp = (int)(i >> 9), k = (int)(i & 511);
    int j = rp / 3, g = rp - j * 3;
    float4 v = *(const float4*)(W_ih + ((long long)(g*512 + j))*1024 + 512 + k);
    *(ushort4*)(wihc3bf + i) = cvt4(v);
  } else if (base < P_WIHE) {                            // whh3: (j*3+g) <- W_hh
    long long i = base - P_WHH3;
    int rp = (int)(i >> 9), k = (int)(i & 511);
    int j = rp / 3, g = rp - j * 3;
    float4 v = *(const float4*)(Whh + ((long long)(g*512 + j))*512 + k);
    *(ushort4*)(whh3bf + i) = cvt4(v);
  } else if (base < P_UA) {                              // wihe: W_ih emb half
    long long i = base - P_WIHE;
    float4 v = *(const float4*)(W_ih + (long long)(i >> 9)*1024 + (i & 511));
    *(ushort4*)(wihebf + i) = cvt4(v);
  } else if (base < P_ENC) {                             // uabf: Ua flat
    long long i = base - P_UA;
    *(ushort4*)(uabf + i) = cvt4(*(const float4*)(Ua + i));
  } else if (base < P_EMB) {                             // encbf: enc flat
    long long i = base - P_ENC;
    *(ushort4*)(encbf + i) = cvt4(*(const float4*)(enc + i));
  } else if (base < P_HINIT) {                           // embbf: gather rows m=t*64+b
    long long i = base - P_EMB;
    int m = (int)(i >> 9), k = (int)(i & 511);
    int t = m >> 6, b = m & 63;
    int tk = (t == 0) ? 0 : tgt[b*TT + t - 1];
    float4 v = *(const float4*)(emb + (long long)tk*HH + k);
    *(ushort4*)(embbf + i) = cvt4(v);
  } else if (base < P_BCAT) {                            // hinit: eh -> hbf0 + h320
    long long i = base - P_HINIT;
    float4 v = *(const float4*)(eh + i);
    *(ushort4*)(hbf0 + i) = cvt4(v);
    *(float4*)(h320 + i) = v;
  } else {                                               // bcat: [ba ; bhh]
    long long i = base - P_BCAT;
    #pragma unroll
    for (int u = 0; u < 4; ++u) {
      long long j = i + u;
      bcat[j] = (j < 512) ? ba[j] : bhh[j - 512];
    }
  }
}

// ---------------------------------------------------------------------------
// cvt for W_out (runs after recurrence; wbf aliases dead regions)
// ---------------------------------------------------------------------------
__global__ __launch_bounds__(256) void cvt_f2b_kernel(const float* __restrict__ in,
    unsigned short* __restrict__ outp, long long n)
{
  long long i = ((long long)blockIdx.x * 256 + threadIdx.x) * 4;
  if (i >= n) return;
  *(ushort4*)(outp + i) = cvt4(*(const float4*)(in + i));
}

// ---------------------------------------------------------------------------
// Generic NT MFMA GEMM: C[m][n] = A[m,:512].B[n,:512] + bias[n]
// SWAP=1: m tiles on blockIdx.x (fastest) so consecutive blocks share B panel.
// ---------------------------------------------------------------------------
template<int OUTBF, int SWAP>
__global__ __launch_bounds__(256) void mfma_nt(const unsigned short* __restrict__ A,
    const unsigned short* __restrict__ Bw, const float* __restrict__ bias,
    void* __restrict__ Cv, long long ldc)
{
  __shared__ unsigned short As[128*32];
  __shared__ unsigned short Bs[128*32];
  const int tid = threadIdx.x;
  const int w = tid >> 6, l = tid & 63;
  const int m0 = (SWAP ? blockIdx.x : blockIdx.y) * 128;
  const int n0 = (SWAP ? blockIdx.y : blockIdx.x) * 128;
  const int wr = w >> 1, wc = w & 1;

  f32x4 acc[4][4];
  #pragma unroll
  for (int i = 0; i < 4; i++)
    #pragma unroll
    for (int j = 0; j < 4; j++) acc[i][j] = (f32x4){0.f, 0.f, 0.f, 0.f};

  const int srow = l >> 2;
  const int scol = (l & 3) * 8;

  for (int k0 = 0; k0 < HH; k0 += 32) {
    __syncthreads();
    #pragma unroll
    for (int q = 0; q < 2; ++q) {
      int r = w*32 + q*16 + srow;
      GLDS(A  + (long long)(m0 + r)*HH + k0 + scol, As + r*32 + scol);
      GLDS(Bw + (long long)(n0 + r)*HH + k0 + scol, Bs + r*32 + scol);
    }
    __syncthreads();

    bf16x8 a[4], b[4];
    #pragma unroll
    for (int mi = 0; mi < 4; mi++)
      a[mi] = *(const bf16x8*)&As[(wr*64 + mi*16 + (l & 15))*32 + (l >> 4)*8];
    #pragma unroll
    for (int ni = 0; ni < 4; ni++)
      b[ni] = *(const bf16x8*)&Bs[(wc*64 + ni*16 + (l & 15))*32 + (l >> 4)*8];
    #pragma unroll
    for (int mi = 0; mi < 4; mi++)
      #pragma unroll
      for (int ni = 0; ni < 4; ni++)
        acc[mi][ni] = __builtin_amdgcn_mfma_f32_16x16x32_bf16(a[mi], b[ni], acc[mi][ni], 0, 0, 0);
  }

  #pragma unroll
  for (int mi = 0; mi < 4; mi++) {
    #pragma unroll
    for (int ni = 0; ni < 4; ni++) {
      int col = n0 + wc*64 + ni*16 + (l & 15);
      float bb = bias[col];
      #pragma unroll
      for (int r2 = 0; r2 < 4; r2++) {
        int row = m0 + wr*64 + mi*16 + (l >> 4)*4 + r2;
        float v = acc[mi][ni][r2] + bb;
        if (OUTBF) ((unsigned short*)Cv)[(long long)row*ldc + col] = f2b(v);
        else       ((float*)Cv)[(long long)row*ldc + col] = v;
      }
    }
  }
}

// ---------------------------------------------------------------------------
// qinit: qbuf[64][512] = h0 @ Wa^T (no bias). grid 4, 256 thr.
// ---------------------------------------------------------------------------
__global__ __launch_bounds__(256) void qinit_mfma(
    const unsigned short* __restrict__ hbf_r, const unsigned short* __restrict__ wabf,
    float* __restrict__ qbuf)
{
  __shared__ unsigned short As[64*32];
  __shared__ unsigned short Bs[128*32];
  const int tid = threadIdx.x;
  const int w = tid >> 6, l = tid & 63;
  const int n0 = blockIdx.x * 128;
  const int wr = w >> 1, wc = w & 1;

  f32x4 acc[2][4];
  #pragma unroll
  for (int i = 0; i < 2; i++)
    #pragma unroll
    for (int j = 0; j < 4; j++) acc[i][j] = (f32x4){0.f, 0.f, 0.f, 0.f};

  const int ar = tid >> 2;
  const int ac8 = (tid & 3) * 8;

  for (int k0 = 0; k0 < HH; k0 += 32) {
    __syncthreads();
    GLDS(hbf_r + (long long)ar*HH + k0 + ac8, As + ar*32 + ac8);
    #pragma unroll
    for (int q = 0; q < 2; ++q) {
      int r = q*64 + ar;
      GLDS(wabf + (long long)(n0 + r)*HH + k0 + ac8, Bs + r*32 + ac8);
    }
    __syncthreads();

    bf16x8 a[2], b[4];
    #pragma unroll
    for (int mi = 0; mi < 2; mi++)
      a[mi] = *(const bf16x8*)&As[(wr*32 + mi*16 + (l & 15))*32 + (l >> 4)*8];
    #pragma unroll
    for (int ni = 0; ni < 4; ni++)
      b[ni] = *(const bf16x8*)&Bs[(wc*64 + ni*16 + (l & 15))*32 + (l >> 4)*8];
    #pragma unroll
    for (int mi = 0; mi < 2; mi++)
      #pragma unroll
      for (int ni = 0; ni < 4; ni++)
        acc[mi][ni] = __builtin_amdgcn_mfma_f32_16x16x32_bf16(a[mi], b[ni], acc[mi][ni], 0, 0, 0);
  }

  #pragma unroll
  for (int mi = 0; mi < 2; mi++) {
    #pragma unroll
    for (int ni = 0; ni < 4; ni++) {
      int col = n0 + wc*64 + ni*16 + (l & 15);
      #pragma unroll
      for (int r2 = 0; r2 < 4; r2++) {
        int row = wr*32 + mi*16 + (l >> 4)*4 + r2;
        qbuf[(long long)row*512 + col] = acc[mi][ni][r2];
      }
    }
  }
}

// ---------------------------------------------------------------------------
// attn for batch b = blockIdx.x, 512 thr. q = bcat + (qbuf | sum of 16 qPart).
// ---------------------------------------------------------------------------
__global__ __launch_bounds__(512) void attn_kernel(int t, int first,
    const float* __restrict__ qbuf, const float* __restrict__ qPart,
    const float* __restrict__ bcat, const unsigned short* __restrict__ ukbf,
    const unsigned short* __restrict__ encbf, const float* __restrict__ Va,
    const float* __restrict__ bvp,
    unsigned short* __restrict__ ctxbf, float* __restrict__ attn_out)
{
  const int b = blockIdx.x, tid = threadIdx.x;
  __shared__ float qs2[8][68];
  __shared__ float vsh[8][68];
  __shared__ float sc[SS], sw[SS];

  {
    const int c = tid;
    float q = bcat[c];
    if (first) {
      q += qbuf[(long long)b*512 + c];
    } else {
      #pragma unroll
      for (int i = 0; i < 16; ++i)
        q += qPart[(long long)i*32768 + b*512 + c];
    }
    qs2[c >> 6][c & 63] = q;
    vsh[c >> 6][c & 63] = Va[c];
  }
  __syncthreads();

  // scores: (s = tid>>3, sub = tid&7), 64 k each
  {
    const int s = tid >> 3, sub = tid & 7;
    const uint4* up = (const uint4*)(ukbf + ((long long)(b*SS + s))*512 + sub*64);
    const float* qp = &qs2[sub][0];
    const float* vp = &vsh[sub][0];
    float p_ = 0.f;
    #pragma unroll
    for (int i = 0; i < 8; ++i) {
      uint4 uv = up[i];
      int e = i*8;
      p_ = fmaf(vp[e+0], tanh_fast(qp[e+0] + bc(uv.x << 16)), p_);
      p_ = fmaf(vp[e+1], tanh_fast(qp[e+1] + bc(uv.x & 0xffff0000u)), p_);
      p_ = fmaf(vp[e+2], tanh_fast(qp[e+2] + bc(uv.y << 16)), p_);
      p_ = fmaf(vp[e+3], tanh_fast(qp[e+3] + bc(uv.y & 0xffff0000u)), p_);
      p_ = fmaf(vp[e+4], tanh_fast(qp[e+4] + bc(uv.z << 16)), p_);
      p_ = fmaf(vp[e+5], tanh_fast(qp[e+5] + bc(uv.z & 0xffff0000u)), p_);
      p_ = fmaf(vp[e+6], tanh_fast(qp[e+6] + bc(uv.w << 16)), p_);
      p_ = fmaf(vp[e+7], tanh_fast(qp[e+7] + bc(uv.w & 0xffff0000u)), p_);
    }
    p_ += __shfl_xor(p_, 1);
    p_ += __shfl_xor(p_, 2);
    p_ += __shfl_xor(p_, 4);
    if (sub == 0) sc[s] = p_ + bvp[0];
  }
  __syncthreads();

  if (tid < 64) {
    float x = sc[tid], mx = x;
    #pragma unroll
    for (int off = 32; off; off >>= 1) mx = fmaxf(mx, __shfl_xor(mx, off));
    float e = __expf(x - mx), sm = e;
    #pragma unroll
    for (int off = 32; off; off >>= 1) sm += __shfl_xor(sm, off);
    float w_ = e * frcp(sm);
    sw[tid] = w_;
    attn_out[((long long)b*TT + t)*SS + tid] = w_;
  }
  __syncthreads();

  {
    float a = 0.f;
    const unsigned short* ep = encbf + (long long)b*SS*512 + tid;
    #pragma unroll 8
    for (int s = 0; s < SS; ++s)
      a = fmaf(sw[s], b2f(ep[s*512]), a);
    ctxbf[b*512 + tid] = f2b(a);
  }
}

// ---------------------------------------------------------------------------
// gates_qgh: gh + gic (two gate-interleaved 64x96 MFMA GEMMs) + gates + h,
// then q-partial for step t+1: qPart[bid] = h_new[:, kslice] @ Wa[:, kslice]^T.
// grid 16 (j0 = kslice = blockIdx.x*32), 256 thr.
// ---------------------------------------------------------------------------
__global__ __launch_bounds__(256) void gates_qgh_mfma(int t, int last,
    const unsigned short* __restrict__ hbf_r, const unsigned short* __restrict__ ctxbf,
    const unsigned short* __restrict__ wihc3bf, const unsigned short* __restrict__ whh3bf,
    const unsigned short* __restrict__ wabf, const float* __restrict__ bcat,
    const unsigned short* __restrict__ giembbf,
    const float* __restrict__ h32_r, float* __restrict__ h32_w,
    unsigned short* __restrict__ hbf_w, unsigned short* __restrict__ hsall,
    float* __restrict__ out_ht, float* __restrict__ qPart)
{
  __shared__ unsigned short As[64*32];   // ctx tile
  __shared__ unsigned short Hs[64*32];   // h tile
  __shared__ unsigned short Bs[96*32];   // wihc3 rows
  __shared__ unsigned short Cs[96*32];   // whh3 rows
  __shared__ unsigned short Was[512*32]; // Wa k-slice (all 512 rows x 32 k)
  __shared__ unsigned short hnewp[64*40];// h_new slice, padded rows
  __shared__ float gl[64*100];           // gic [64][96] padded
  __shared__ float hl[64*100];           // gh  [64][96] padded
  const int tid = threadIdx.x;
  const int w = tid >> 6, l = tid & 63;
  const int n0 = blockIdx.x * 96, j0 = blockIdx.x * 32;
  const int wr = w >> 1, wc = w & 1;

  f32x4 accg[2][3], acch[2][3];
  #pragma unroll
  for (int i = 0; i < 2; i++)
    #pragma unroll
    for (int j = 0; j < 3; j++) {
      accg[i][j] = (f32x4){0.f, 0.f, 0.f, 0.f};
      acch[i][j] = (f32x4){0.f, 0.f, 0.f, 0.f};
    }

  for (int k0 = 0; k0 < HH; k0 += 32) {
    __syncthreads();
    #pragma unroll
    for (int q = 0; q < 5; ++q) {
      int idx = tid + q*256;                    // 0..1279
      if (idx < 256) {
        int r = idx >> 2, c8 = (idx & 3) * 8;
        GLDS(ctxbf + (long long)r*HH + k0 + c8, As + r*32 + c8);
      } else if (idx < 512) {
        int i2 = idx - 256, r = i2 >> 2, c8 = (i2 & 3) * 8;
        GLDS(hbf_r + (long long)r*HH + k0 + c8, Hs + r*32 + c8);
      } else if (idx < 896) {
        int i2 = idx - 512, r = i2 >> 2, c8 = (i2 & 3) * 8;
        GLDS(wihc3bf + (long long)(n0 + r)*HH + k0 + c8, Bs + r*32 + c8);
      } else {
        int i2 = idx - 896, r = i2 >> 2, c8 = (i2 & 3) * 8;
        GLDS(whh3bf + (long long)(n0 + r)*HH + k0 + c8, Cs + r*32 + c8);
      }
    }
    __syncthreads();

    bf16x8 ag[2], ah[2], bg[3], bh[3];
    #pragma unroll
    for (int mi = 0; mi < 2; mi++) {
      ag[mi] = *(const bf16x8*)&As[(wr*32 + mi*16 + (l & 15))*32 + (l >> 4)*8];
      ah[mi] = *(const bf16x8*)&Hs[(wr*32 + mi*16 + (l & 15))*32 + (l >> 4)*8];
    }
    #pragma unroll
    for (int ni = 0; ni < 3; ni++) {
      bg[ni] = *(const bf16x8*)&Bs[(wc*48 + ni*16 + (l & 15))*32 + (l >> 4)*8];
      bh[ni] = *(const bf16x8*)&Cs[(wc*48 + ni*16 + (l & 15))*32 + (l >> 4)*8];
    }
    #pragma unroll
    for (int mi = 0; mi < 2; mi++)
      #pragma unroll
      for (int ni = 0; ni < 3; ni++) {
        accg[mi][ni] = __builtin_amdgcn_mfma_f32_16x16x32_bf16(ag[mi], bg[ni], accg[mi][ni], 0, 0, 0);
        acch[mi][ni] = __builtin_amdgcn_mfma_f32_16x16x32_bf16(ah[mi], bh[ni], acch[mi][ni], 0, 0, 0);
      }
  }

  // prefetch Wa k-slice for the q-partial pass (overlaps gl/hl + gates)
  if (!last) {
    #pragma unroll
    for (int q = 0; q < 8; ++q) {
      int idx = tid + q*256;                    // 0..2047
      int r = idx >> 2, c8 = (idx & 3) * 8;
      GLDS(wabf + (long long)r*HH + j0 + c8, Was + r*32 + c8);
    }
  }

  #pragma unroll
  for (int mi = 0; mi < 2; mi++)
    #pragma unroll
    for (int ni = 0; ni < 3; ni++) {
      int col = wc*48 + ni*16 + (l & 15);
      #pragma unroll
      for (int r2 = 0; r2 < 4; r2++) {
        int row = wr*32 + mi*16 + (l >> 4)*4 + r2;
        gl[row*100 + col] = accg[mi][ni][r2];
        hl[row*100 + col] = acch[mi][ni][r2];
      }
    }
  __syncthreads();

  // gates: 2048 (b, jj) pairs -> h_new
  for (int i = tid; i < 2048; i += 256) {
    const int b = i >> 5, jj = i & 31, j = j0 + jj;
    float gcr = gl[b*100 + jj*3 + 0];
    float gcz = gl[b*100 + jj*3 + 1];
    float gcn = gl[b*100 + jj*3 + 2];
    float ghr = hl[b*100 + jj*3 + 0] + bcat[512 + j];
    float ghz = hl[b*100 + jj*3 + 1] + bcat[1024 + j];
    float ghn = hl[b*100 + jj*3 + 2] + bcat[1536 + j];
    const long long gb = ((long long)t*BB + b)*H3 + j;
    float gir = b2f(giembbf[gb]);
    float giz = b2f(giembbf[gb + 512]);
    float gin = b2f(giembbf[gb + 1024]);
    float r = sigm(gir + gcr + ghr);
    float z = sigm(giz + gcz + ghz);
    float n = tanh_fast(gin + gcn + r * ghn);
    float hold = h32_r[b*512 + j];
    float hn = (1.f - z) * n + z * hold;
    h32_w[b*512 + j] = hn;
    unsigned short hb = f2b(hn);
    hbf_w[b*512 + j] = hb;
    hsall[((long long)b*TT + t)*512 + j] = hb;
    hnewp[b*40 + jj] = hb;
    if (t == TT - 1) out_ht[b*512 + j] = hn;
  }
  __syncthreads();

  // q-partial: qPart[bid][b][n] = h_new[b][kslice] . Wa[n][kslice]  (K=32, one MFMA)
  if (!last) {
    f32x4 qa[4][8];
    #pragma unroll
    for (int mi = 0; mi < 4; mi++)
      #pragma unroll
      for (int ni = 0; ni < 8; ni++) qa[mi][ni] = (f32x4){0.f, 0.f, 0.f, 0.f};

    bf16x8 a[4];
    #pragma unroll
    for (int mi = 0; mi < 4; mi++)
      a[mi] = *(const bf16x8*)&hnewp[(mi*16 + (l & 15))*40 + (l >> 4)*8];
    #pragma unroll
    for (int ni = 0; ni < 8; ni++) {
      bf16x8 bfr = *(const bf16x8*)&Was[(w*128 + ni*16 + (l & 15))*32 + (l >> 4)*8];
      #pragma unroll
      for (int mi = 0; mi < 4; mi++)
        qa[mi][ni] = __builtin_amdgcn_mfma_f32_16x16x32_bf16(a[mi], bfr, qa[mi][ni], 0, 0, 0);
    }

    float* qp = qPart + (long long)blockIdx.x * 32768;
    #pragma unroll
    for (int mi = 0; mi < 4; mi++)
      #pragma unroll
      for (int ni = 0; ni < 8; ni++) {
        int col = w*128 + ni*16 + (l & 15);
        #pragma unroll
        for (int r2 = 0; r2 < 4; r2++) {
          int row = mi*16 + (l >> 4)*4 + r2;
          qp[row*512 + col] = qa[mi][ni][r2];
        }
      }
  }
}

// ---------------------------------------------------------------------------
// In-place log-softmax, register-resident: one read pass, one write pass.
// ---------------------------------------------------------------------------
__global__ __launch_bounds__(1024) void logsoftmax_kernel(float* __restrict__ lp)
{
  float4* p4 = (float4*)(lp + (long long)blockIdx.x * VV);
  const int tid = threadIdx.x;
  float4 x[8];
  float m = -1e30f, s = 0.f;
  #pragma unroll
  for (int i = 0; i < 8; ++i) {
    int v = tid + i*1024;
    if (v < 8000) {
      float4 xx = p4[v];
      x[i] = xx;
      float mx = fmaxf(fmaxf(xx.x, xx.y), fmaxf(xx.z, xx.w));
      float e = __expf(xx.x - mx) + __expf(xx.y - mx) + __expf(xx.z - mx) + __expf(xx.w - mx);
      if (mx > m) { s = s * __expf(m - mx) + e; m = mx; }
      else        { s += e * __expf(mx - m); }
    }
  }
  #pragma unroll
  for (int off = 32; off; off >>= 1) {
    float m2 = __shfl_xor(m, off), s2 = __shfl_xor(s, off);
    float mm = fmaxf(m, m2);
    s = s * __expf(m - mm) + s2 * __expf(m2 - mm);
    m = mm;
  }
  __shared__ float rm[16], rs[16];
  if ((tid & 63) == 0) { rm[tid >> 6] = m; rs[tid >> 6] = s; }
  __syncthreads();
  float M = rm[0], S = rs[0];
  #pragma unroll
  for (int i = 1; i < 16; ++i) {
    float m2 = rm[i], s2 = rs[i];
    float mm = fmaxf(M, m2);
    S = S * __expf(M - mm) + s2 * __expf(m2 - mm);
    M = mm;
  }
  const float L = M + logf(S);
  #pragma unroll
  for (int i = 0; i < 8; ++i) {
    int v = tid + i*1024;
    if (v < 8000) {
      float4 xx = x[i];
      xx.x -= L; xx.y -= L; xx.z -= L; xx.w -= L;
      p4[v] = xx;
    }
  }
}

// ---------------------------------------------------------------------------
extern "C" void kernel_launch(void* const* d_in, const int* in_sizes, int n_in,
                              void* d_out, int out_size, void* d_ws, size_t ws_size,
                              hipStream_t stream)
{
  const float* enc   = (const float*)d_in[0];
  const float* eh    = (const float*)d_in[1];
  const int*   tgt   = (const int*)  d_in[2];
  const float* emb   = (const float*)d_in[3];
  const float* Wa    = (const float*)d_in[4];
  const float* ba    = (const float*)d_in[5];
  const float* Ua    = (const float*)d_in[6];
  const float* bu    = (const float*)d_in[7];
  const float* Va    = (const float*)d_in[8];
  const float* bvp   = (const float*)d_in[9];
  const float* W_ih  = (const float*)d_in[10];
  const float* W_hh  = (const float*)d_in[11];
  const float* b_ih  = (const float*)d_in[12];
  const float* b_hh  = (const float*)d_in[13];
  const float* W_out = (const float*)d_in[14];
  const float* b_out = (const float*)d_in[15];

  float* out = (float*)d_out;
  float* ws  = (float*)d_ws;

  unsigned short* giembbf = (unsigned short*)(ws + WS_GIEMBBF);
  unsigned short* ukbf    = (unsigned short*)(ws + WS_UKBF);
  unsigned short* encbf   = (unsigned short*)(ws + WS_ENCBF);
  unsigned short* embbf   = (unsigned short*)(ws + WS_EMBBF);
  unsigned short* wcatbf  = (unsigned short*)(ws + WS_WCATBF);
  unsigned short* wihc3bf = (unsigned short*)(ws + WS_WIHC3);
  unsigned short* wihebf  = (unsigned short*)(ws + WS_WIHE);
  unsigned short* uabf    = (unsigned short*)(ws + WS_UABF);
  unsigned short* whh3bf  = (unsigned short*)(ws + WS_WHH3);
  float* bcat  = ws + WS_BCAT;
  float* qbuf  = ws + WS_QBUF;
  float* qPart = ws + WS_QPART;
  unsigned short* ctxbf = (unsigned short*)(ws + WS_CTXBF);
  float* h320 = ws + WS_H32;
  float* h321 = h320 + BB*HH;
  unsigned short* hbf0 = (unsigned short*)(ws + WS_HBF);
  unsigned short* hbf1 = hbf0 + BB*HH;
  unsigned short* hsall = (unsigned short*)(ws + WS_HSALL);
  unsigned short* wbf   = (unsigned short*)ws;   // aliases dead region post-recurrence

  float* attn_out = out + OUT_ATT;
  float* out_ht   = out + OUT_HT;

  // ---- prep: single fused conversion kernel ----
  prep_all<<<dim3((unsigned)(P_TOT/1024)), dim3(256), 0, stream>>>(
      Wa, W_hh, ba, b_hh, W_ih, Ua, enc, emb, tgt, eh,
      wcatbf, wihc3bf, whh3bf, wihebf, uabf, encbf, embbf, hbf0, h320, bcat);

  // Uk (bf16 out) and GiEmb (bf16 out) via MFMA
  mfma_nt<1,0><<<dim3(4, 32), dim3(256), 0, stream>>>(encbf, uabf, bu, (void*)ukbf, (long long)HH);
  mfma_nt<1,0><<<dim3(12, 32), dim3(256), 0, stream>>>(embbf, wihebf, b_ih, (void*)giembbf, (long long)H3);

  // q(0) = h0 @ Wa^T (no bias; attn adds bcat)
  qinit_mfma<<<dim3(4), dim3(256), 0, stream>>>(hbf0, wcatbf, qbuf);

  // ---- recurrence: 2 launches/step ----
  for (int t = 0; t < TT; ++t) {
    const unsigned short* hr  = (t & 1) ? hbf1 : hbf0;
    const float*          h32r = (t & 1) ? h321 : h320;
    unsigned short*       hw  = (t & 1) ? hbf0 : hbf1;
    float*                h32w = (t & 1) ? h320 : h321;
    attn_kernel<<<dim3(64), dim3(512), 0, stream>>>(t, (t == 0) ? 1 : 0, qbuf, qPart,
        bcat, ukbf, encbf, Va, bvp, ctxbf, attn_out);
    gates_qgh_mfma<<<dim3(16), dim3(256), 0, stream>>>(t, (t == TT - 1) ? 1 : 0,
        hr, ctxbf, wihc3bf, whh3bf, wcatbf, bcat, giembbf,
        h32r, h32w, hw, hsall, out_ht, qPart);
  }

  // ---- output projection + log-softmax ----
  cvt_f2b_kernel<<<dim3(16000), dim3(256), 0, stream>>>(W_out, wbf, (long long)VV*HH);
  // grid transposed: m tiles on x (fastest) so 32 consecutive blocks share a B panel
  mfma_nt<0,1><<<dim3(32, 250), dim3(256), 0, stream>>>(hsall, wbf, b_out, (void*)out, (long long)VV);
  logsoftmax_kernel<<<dim3(4096), dim3(1024), 0, stream>>>(out);
}